// Round 9
// baseline (10618.204 us; speedup 1.0000x reference)
//
#include <hip/hip_runtime.h>
#include <hip/hip_bf16.h>

// SSNet: 2-layer flag-gated LSTM, persistent-tile MFMA implementation.
// B=16384, T=32, IN=64, H=512, OUT=19.
// R9 = R8 with the register handcuffs removed. __launch_bounds__(1024, 4)
// was interpreted as min 4 BLOCKS/CU (CUDA semantics) -> 16 waves/SIMD ->
// VGPR budget 64 since R4 (R1/R2 with (512,2) got 128). That 64-reg budget
// forced per-chunk scratch reloads of the pipeline's base pointers
// (~8 GB read-only FETCH excess, serialized inner loop, MfmaUtil 13%).
// A 1024-thread WG needs VGPR<=128 to launch at all, so plain
// __launch_bounds__(1024) gives the full 128 budget; LDS already caps
// occupancy at 1 WG/CU, so nothing is lost.

#define T_STEPS 32
#define IN_F    64
#define HID     512
#define OUT_F   19
#define BW      64   // batch rows per WG

typedef short bf16x8 __attribute__((ext_vector_type(8)));   // 8 bf16 = 4 VGPRs
typedef float f32x4  __attribute__((ext_vector_type(4)));

__device__ __forceinline__ float fast_sig(float x) {
    return __builtin_amdgcn_rcpf(1.0f + __expf(-x));
}
__device__ __forceinline__ float fast_tanh(float x) {
    return 1.0f - 2.0f * __builtin_amdgcn_rcpf(1.0f + __expf(2.0f * x));
}
__device__ __forceinline__ unsigned pack2(float a, float b) {
    return ((unsigned)__bfloat16_as_ushort(__float2bfloat16(b)) << 16)
         |  (unsigned)__bfloat16_as_ushort(__float2bfloat16(a));
}

// Light barrier: LDS hazards only (don't drain vmcnt -> nt stores fly on).
#define LBAR() do { \
    asm volatile("s_waitcnt lgkmcnt(0)" ::: "memory"); \
    __builtin_amdgcn_sched_barrier(0); \
    __builtin_amdgcn_s_barrier(); \
    __builtin_amdgcn_sched_barrier(0); \
} while (0)

#define MFMA8(x0, x1, q0, q1, q2, q3) do { \
    acc[0][0] = __builtin_amdgcn_mfma_f32_16x16x32_bf16(x0, q0, acc[0][0], 0, 0, 0); \
    acc[1][0] = __builtin_amdgcn_mfma_f32_16x16x32_bf16(x1, q0, acc[1][0], 0, 0, 0); \
    acc[0][1] = __builtin_amdgcn_mfma_f32_16x16x32_bf16(x0, q1, acc[0][1], 0, 0, 0); \
    acc[1][1] = __builtin_amdgcn_mfma_f32_16x16x32_bf16(x1, q1, acc[1][1], 0, 0, 0); \
    acc[0][2] = __builtin_amdgcn_mfma_f32_16x16x32_bf16(x0, q2, acc[0][2], 0, 0, 0); \
    acc[1][2] = __builtin_amdgcn_mfma_f32_16x16x32_bf16(x1, q2, acc[1][2], 0, 0, 0); \
    acc[0][3] = __builtin_amdgcn_mfma_f32_16x16x32_bf16(x0, q3, acc[0][3], 0, 0, 0); \
    acc[1][3] = __builtin_amdgcn_mfma_f32_16x16x32_bf16(x1, q3, acc[1][3], 0, 0, 0); \
} while (0)

// Packed B layout, per 16-col block cb of the 2048 gate-cols:
//   dst[cb*(K*16) + kc*512 + l15*32 + lq*8 + e] = W[kc*32+lq*8+e + rowOff][cb*16+l15]
__global__ void wprep_kernel(const float* __restrict__ src,
                             __hip_bfloat16* __restrict__ dst,
                             int kcBits, int rowOff) {
    int idx = blockIdx.x * 256 + threadIdx.x;
    int total = 2048 << (kcBits + 5);
    if (idx >= total) return;
    int e   = idx & 7;
    int lq  = (idx >> 3) & 3;
    int l15 = (idx >> 5) & 15;
    int kc  = (idx >> 9) & ((1 << kcBits) - 1);
    int cb  = idx >> (9 + kcBits);
    int k   = kc * 32 + lq * 8 + e + rowOff;
    int col = cb * 16 + l15;
    dst[idx] = __float2bfloat16(src[(size_t)k * 2048 + col]);
}

// Statically-addressed GEMM section: KC chunks, depth-2 rotated pipeline.
template<int KC, int RT1>
__device__ __forceinline__ void gemm_sec(const char* aE, const char* aO,
                                         const __hip_bfloat16* b0p,
                                         const __hip_bfloat16* b1p,
                                         const __hip_bfloat16* b2p,
                                         const __hip_bfloat16* b3p,
                                         f32x4 acc[2][4]) {
    bf16x8 pa0, pa1, pa2, pa3, pb0, pb1, pb2, pb3, x0, x1;
    pa0 = *(const bf16x8*)(b0p);
    pa1 = *(const bf16x8*)(b1p);
    pa2 = *(const bf16x8*)(b2p);
    pa3 = *(const bf16x8*)(b3p);
    #pragma unroll 1
    for (int m = 0; m < KC - 2; m += 2) {
        const int ao = (m >> 1) * 128;
        pb0 = *(const bf16x8*)(b0p + (m + 1) * 512);
        pb1 = *(const bf16x8*)(b1p + (m + 1) * 512);
        pb2 = *(const bf16x8*)(b2p + (m + 1) * 512);
        pb3 = *(const bf16x8*)(b3p + (m + 1) * 512);
        x0 = *(const bf16x8*)(aE + ao);
        x1 = *(const bf16x8*)(aE + RT1 + ao);
        MFMA8(x0, x1, pa0, pa1, pa2, pa3);
        pa0 = *(const bf16x8*)(b0p + (m + 2) * 512);
        pa1 = *(const bf16x8*)(b1p + (m + 2) * 512);
        pa2 = *(const bf16x8*)(b2p + (m + 2) * 512);
        pa3 = *(const bf16x8*)(b3p + (m + 2) * 512);
        x0 = *(const bf16x8*)(aO + ao);
        x1 = *(const bf16x8*)(aO + RT1 + ao);
        MFMA8(x0, x1, pb0, pb1, pb2, pb3);
    }
    // tail: chunks KC-2 (even, in pa) and KC-1 (odd)
    {
        const int ao = ((KC - 2) >> 1) * 128;
        pb0 = *(const bf16x8*)(b0p + (KC - 1) * 512);
        pb1 = *(const bf16x8*)(b1p + (KC - 1) * 512);
        pb2 = *(const bf16x8*)(b2p + (KC - 1) * 512);
        pb3 = *(const bf16x8*)(b3p + (KC - 1) * 512);
        x0 = *(const bf16x8*)(aE + ao);
        x1 = *(const bf16x8*)(aE + RT1 + ao);
        MFMA8(x0, x1, pa0, pa1, pa2, pa3);
        x0 = *(const bf16x8*)(aO + ao);
        x1 = *(const bf16x8*)(aO + RT1 + ao);
        MFMA8(x0, x1, pb0, pb1, pb2, pb3);
    }
}

__global__ __attribute__((amdgpu_waves_per_eu(4))) __launch_bounds__(1024)
void lstm_main(const float* __restrict__ x,
               const float* __restrict__ b0v,
               const float* __restrict__ Wx1,     // row 0 = flag weights (f32)
               const float* __restrict__ b1v,
               const float* __restrict__ Wlin,
               const float* __restrict__ blin,
               const __hip_bfloat16* __restrict__ Wx0p,
               const __hip_bfloat16* __restrict__ Wh0p,
               const __hip_bfloat16* __restrict__ Wx1hp,
               const __hip_bfloat16* __restrict__ Wh1p,
               float* __restrict__ cws,
               float* __restrict__ hws,
               float* __restrict__ out)
{
    // LDS h tiles: row-major bf16, row stride 1024B, XOR-swizzle (row&7)<<4
    __shared__ __align__(16) __hip_bfloat16 h0s[BW * HID];   // 64 KB
    __shared__ __align__(16) __hip_bfloat16 h1s[BW * HID];   // 64 KB
    __shared__ __align__(16) __hip_bfloat16 xs[BW * IN_F];   // 8 KB, row stride 128B
    __shared__ float flags[BW];

    const int tid  = threadIdx.x;
    const int lane = tid & 63;
    const int wid  = tid >> 6;      // 0..15
    const int rg   = wid & 1;       // 2 row-groups of 32 rows
    const int cg   = wid >> 1;      // 8 col-groups of 64 gate-cols (per gate)
    const int l15  = lane & 15;
    const int lq   = lane >> 4;
    const int lq16 = lq * 16;
    const int laneoff = l15 * 32 + lq * 8;
    const int rbase = rg * 32;
    const int asw  = (l15 & 7) << 4;        // rbase % 8 == 0
    const int wg   = blockIdx.x;
    const size_t bbase = (size_t)wg * BW;
    const char* xsC = (const char*)xs;
    const char* h0C = (const char*)h0s;

    // pre-swizzled A bases: even chunks (k-bit6 clear) / odd chunks (set)
    const int swE = lq16 ^ asw;
    const int swO = (64 + lq16) ^ asw;
    const char* ahE = h0C + (rbase + l15) * 1024 + swE;
    const char* ahO = h0C + (rbase + l15) * 1024 + swO;
    const int h1d = (int)((const char*)h1s - (const char*)h0s);
    const char* axE = xsC + (rbase + l15) * 128 + swE;
    const char* axO = xsC + (rbase + l15) * 128 + swO;

    // zero h LDS
    {
        int4 z; z.x = z.y = z.z = z.w = 0;
        int4* p0 = (int4*)h0s; int4* p1 = (int4*)h1s;
        for (int i = tid; i < BW * HID * 2 / 16; i += 1024) { p0[i] = z; p1[i] = z; }
    }
    // stage x(0) + flags
    for (int i = tid; i < BW * IN_F; i += 1024) {
        int row = i >> 6, k = i & 63;
        float v = __builtin_nontemporal_load(&x[(bbase + row) * (T_STEPS * IN_F) + k]);
        int byte = row * 128 + ((2 * k) ^ ((row & 7) << 4));
        *(__hip_bfloat16*)((char*)xs + byte) = __float2bfloat16(v);
    }
    if (tid < BW) flags[tid] = x[(bbase + tid) * (T_STEPS * IN_F)];
    LBAR();

    const size_t wsWG0 = (size_t)(0 * 256 + wg) * 32768;   // floats
    const size_t wsWG1 = (size_t)(1 * 256 + wg) * 32768;

    #pragma unroll 1
    for (int t = 0; t < T_STEPS; ++t) {
        unsigned hnr[4][2][2];   // packed bf16 h_new [sb][rt][pair] (static idx)

        // ================= Layer 0: g0 = x@Wx0 + h0@Wh0 + b0 =================
        #pragma unroll
        for (int sb = 0; sb < 4; ++sb) {
            const int cgsb = cg * 4 + sb;
            const size_t sbase = wsWG0 + (size_t)((wid * 4 + sb) * 2) * 256 + lane * 4;
            f32x4 cold[2], hold[2];
            if (t > 0) {
                cold[0] = __builtin_nontemporal_load((const f32x4*)(cws + sbase));
                cold[1] = __builtin_nontemporal_load((const f32x4*)(cws + sbase + 256));
                hold[0] = __builtin_nontemporal_load((const f32x4*)(hws + sbase));
                hold[1] = __builtin_nontemporal_load((const f32x4*)(hws + sbase + 256));
            } else {
                f32x4 zz = {0.f, 0.f, 0.f, 0.f};
                cold[0] = zz; cold[1] = zz; hold[0] = zz; hold[1] = zz;
            }
            __builtin_amdgcn_sched_barrier(0);   // pin state-load issue here

            f32x4 acc[2][4];
            { f32x4 zz = {0.f, 0.f, 0.f, 0.f};
              #pragma unroll
              for (int rt = 0; rt < 2; ++rt)
                  #pragma unroll
                  for (int g = 0; g < 4; ++g) acc[rt][g] = zz; }

            // x part: 2 chunks, straight-line
            {
                const __hip_bfloat16* bx0 = Wx0p + (size_t)(0 * 32 + cgsb) * 1024 + laneoff;
                const __hip_bfloat16* bx1 = Wx0p + (size_t)(1 * 32 + cgsb) * 1024 + laneoff;
                const __hip_bfloat16* bx2 = Wx0p + (size_t)(2 * 32 + cgsb) * 1024 + laneoff;
                const __hip_bfloat16* bx3 = Wx0p + (size_t)(3 * 32 + cgsb) * 1024 + laneoff;
                bf16x8 pa0 = *(const bf16x8*)(bx0);
                bf16x8 pa1 = *(const bf16x8*)(bx1);
                bf16x8 pa2 = *(const bf16x8*)(bx2);
                bf16x8 pa3 = *(const bf16x8*)(bx3);
                bf16x8 pb0 = *(const bf16x8*)(bx0 + 512);
                bf16x8 pb1 = *(const bf16x8*)(bx1 + 512);
                bf16x8 pb2 = *(const bf16x8*)(bx2 + 512);
                bf16x8 pb3 = *(const bf16x8*)(bx3 + 512);
                bf16x8 x0 = *(const bf16x8*)(axE);
                bf16x8 x1 = *(const bf16x8*)(axE + 16 * 128);
                MFMA8(x0, x1, pa0, pa1, pa2, pa3);
                x0 = *(const bf16x8*)(axO);
                x1 = *(const bf16x8*)(axO + 16 * 128);
                MFMA8(x0, x1, pb0, pb1, pb2, pb3);
            }
            // h0 part: 16 chunks
            gemm_sec<16, 16 * 1024>(ahE, ahO,
                Wh0p + (size_t)(0 * 32 + cgsb) * 8192 + laneoff,
                Wh0p + (size_t)(1 * 32 + cgsb) * 8192 + laneoff,
                Wh0p + (size_t)(2 * 32 + cgsb) * 8192 + laneoff,
                Wh0p + (size_t)(3 * 32 + cgsb) * 8192 + laneoff, acc);

            const int jcol = cg * 64 + sb * 16 + l15;
            float bia[4];
            #pragma unroll
            for (int g = 0; g < 4; ++g) bia[g] = b0v[g * 512 + jcol];

            #pragma unroll
            for (int rt = 0; rt < 2; ++rt) {
                f32x4 cnew, hnew;
                #pragma unroll
                for (int r = 0; r < 4; ++r) {
                    const float f = flags[rbase + rt * 16 + lq * 4 + r];
                    float gi = acc[rt][0][r] + bia[0];
                    float gf = acc[rt][1][r] + bia[1];
                    float gg = acc[rt][2][r] + bia[2];
                    float go = acc[rt][3][r] + bia[3];
                    float cn = fast_sig(gf) * cold[rt][r] + fast_sig(gi) * fast_tanh(gg);
                    float hn = fast_sig(go) * fast_tanh(cn);
                    cnew[r] = f * cn + (1.f - f) * cold[rt][r];
                    hnew[r] = f * hn + (1.f - f) * hold[rt][r];
                }
                __builtin_nontemporal_store(cnew, (f32x4*)(cws + sbase + rt * 256));
                __builtin_nontemporal_store(hnew, (f32x4*)(hws + sbase + rt * 256));
                hnr[sb][rt][0] = pack2(hnew[0], hnew[1]);
                hnr[sb][rt][1] = pack2(hnew[2], hnew[3]);
            }
        }
        LBAR();   // all waves done reading h0s/xs
        // write new h0 -> LDS directly from registers
        #pragma unroll
        for (int sb = 0; sb < 4; ++sb) {
            const int col2 = 2 * (cg * 64 + sb * 16 + l15);
            #pragma unroll
            for (int rt = 0; rt < 2; ++rt)
                #pragma unroll
                for (int p = 0; p < 2; ++p) {
                    unsigned u = hnr[sb][rt][p];
                    int row = rbase + rt * 16 + lq * 4 + 2 * p;
                    *(unsigned short*)((char*)h0s + row * 1024 + (col2 ^ ((row & 7) << 4))) = (unsigned short)u;
                    ++row;
                    *(unsigned short*)((char*)h0s + row * 1024 + (col2 ^ ((row & 7) << 4))) = (unsigned short)(u >> 16);
                }
        }
        LBAR();   // new h0s visible

        // ===== Layer 1: g1 = flag*Wx1[0] + h0_new@Wx1[1:] + h1@Wh1 + b1 =====
        #pragma unroll
        for (int sb = 0; sb < 4; ++sb) {
            const int cgsb = cg * 4 + sb;
            const size_t sbase = wsWG1 + (size_t)((wid * 4 + sb) * 2) * 256 + lane * 4;
            f32x4 cold[2], hold[2];
            if (t > 0) {
                cold[0] = __builtin_nontemporal_load((const f32x4*)(cws + sbase));
                cold[1] = __builtin_nontemporal_load((const f32x4*)(cws + sbase + 256));
                hold[0] = __builtin_nontemporal_load((const f32x4*)(hws + sbase));
                hold[1] = __builtin_nontemporal_load((const f32x4*)(hws + sbase + 256));
            } else {
                f32x4 zz = {0.f, 0.f, 0.f, 0.f};
                cold[0] = zz; cold[1] = zz; hold[0] = zz; hold[1] = zz;
            }
            __builtin_amdgcn_sched_barrier(0);   // pin state-load issue here

            f32x4 acc[2][4];
            { f32x4 zz = {0.f, 0.f, 0.f, 0.f};
              #pragma unroll
              for (int rt = 0; rt < 2; ++rt)
                  #pragma unroll
                  for (int g = 0; g < 4; ++g) acc[rt][g] = zz; }

            gemm_sec<16, 16 * 1024>(ahE, ahO,
                Wx1hp + (size_t)(0 * 32 + cgsb) * 8192 + laneoff,
                Wx1hp + (size_t)(1 * 32 + cgsb) * 8192 + laneoff,
                Wx1hp + (size_t)(2 * 32 + cgsb) * 8192 + laneoff,
                Wx1hp + (size_t)(3 * 32 + cgsb) * 8192 + laneoff, acc);
            gemm_sec<16, 16 * 1024>(ahE + h1d, ahO + h1d,
                Wh1p + (size_t)(0 * 32 + cgsb) * 8192 + laneoff,
                Wh1p + (size_t)(1 * 32 + cgsb) * 8192 + laneoff,
                Wh1p + (size_t)(2 * 32 + cgsb) * 8192 + laneoff,
                Wh1p + (size_t)(3 * 32 + cgsb) * 8192 + laneoff, acc);

            const int jcol = cg * 64 + sb * 16 + l15;
            float bia[4], w10[4];
            #pragma unroll
            for (int g = 0; g < 4; ++g) {
                bia[g] = b1v[g * 512 + jcol];
                w10[g] = Wx1[g * 512 + jcol];   // Wx1 row 0 (flag weights)
            }
            #pragma unroll
            for (int rt = 0; rt < 2; ++rt) {
                f32x4 cnew, hnew;
                #pragma unroll
                for (int r = 0; r < 4; ++r) {
                    const float f = flags[rbase + rt * 16 + lq * 4 + r];
                    float gi = acc[rt][0][r] + bia[0] + f * w10[0];
                    float gf = acc[rt][1][r] + bia[1] + f * w10[1];
                    float gg = acc[rt][2][r] + bia[2] + f * w10[2];
                    float go = acc[rt][3][r] + bia[3] + f * w10[3];
                    float cn = fast_sig(gf) * cold[rt][r] + fast_sig(gi) * fast_tanh(gg);
                    float hn = fast_sig(go) * fast_tanh(cn);
                    cnew[r] = f * cn + (1.f - f) * cold[rt][r];
                    hnew[r] = f * hn + (1.f - f) * hold[rt][r];
                }
                __builtin_nontemporal_store(cnew, (f32x4*)(cws + sbase + rt * 256));
                __builtin_nontemporal_store(hnew, (f32x4*)(hws + sbase + rt * 256));
                hnr[sb][rt][0] = pack2(hnew[0], hnew[1]);
                hnr[sb][rt][1] = pack2(hnew[2], hnew[3]);
            }
        }
        LBAR();   // all waves done reading h0s/h1s

        // write new h1 -> LDS; stage x(t+1) + flags in the same phase
        #pragma unroll
        for (int sb = 0; sb < 4; ++sb) {
            const int col2 = 2 * (cg * 64 + sb * 16 + l15);
            #pragma unroll
            for (int rt = 0; rt < 2; ++rt)
                #pragma unroll
                for (int p = 0; p < 2; ++p) {
                    unsigned u = hnr[sb][rt][p];
                    int row = rbase + rt * 16 + lq * 4 + 2 * p;
                    *(unsigned short*)((char*)h1s + row * 1024 + (col2 ^ ((row & 7) << 4))) = (unsigned short)u;
                    ++row;
                    *(unsigned short*)((char*)h1s + row * 1024 + (col2 ^ ((row & 7) << 4))) = (unsigned short)(u >> 16);
                }
        }
        if (t + 1 < T_STEPS) {
            for (int i = tid; i < BW * IN_F; i += 1024) {
                int row = i >> 6, k = i & 63;
                float v = __builtin_nontemporal_load(&x[(bbase + row) * (T_STEPS * IN_F) + (t + 1) * IN_F + k]);
                int byte = row * 128 + ((2 * k) ^ ((row & 7) << 4));
                *(__hip_bfloat16*)((char*)xs + byte) = __float2bfloat16(v);
            }
            if (tid < BW) flags[tid] = x[(bbase + tid) * (T_STEPS * IN_F) + (t + 1) * IN_F];
        }
        LBAR();   // h1s/xs/flags ready for next step
    }

    // ---- final linear: out = h1 @ Wlin + blin  (64x512 @ 512x19) ----
    for (int task = tid; task < BW * OUT_F; task += 1024) {
        int o   = task >> 6;     // 0..18, wave-uniform
        int row = task & 63;
        float s = blin[o];
        const float* wl = Wlin + o;
        for (int k = 0; k < HID; ++k) {
            int byte = row * 1024 + ((2 * k) ^ ((row & 7) << 4));
            float hv = __bfloat162float(*(const __hip_bfloat16*)((const char*)h1s + byte));
            s += hv * wl[k * OUT_F];
        }
        out[(bbase + row) * OUT_F + o] = s;
    }
}

extern "C" void kernel_launch(void* const* d_in, const int* in_sizes, int n_in,
                              void* d_out, int out_size, void* d_ws, size_t ws_size,
                              hipStream_t stream) {
    const float* x    = (const float*)d_in[0];
    const float* Wx0  = (const float*)d_in[1];
    const float* Wh0  = (const float*)d_in[2];
    const float* b0   = (const float*)d_in[3];
    const float* Wx1  = (const float*)d_in[4];
    const float* Wh1  = (const float*)d_in[5];
    const float* b1   = (const float*)d_in[6];
    const float* Wlin = (const float*)d_in[7];
    const float* blin = (const float*)d_in[8];

    // workspace carve (bytes)
    const size_t offWx0p  = 0;                       // 2048*64*2   = 262144
    const size_t offWh0p  = 262144;                  // 2048*512*2  = 2097152
    const size_t offWx1hp = 2359296;
    const size_t offWh1p  = 4456448;
    const size_t offC     = 6553600;                 // 2*256*32768*4 = 67108864
    const size_t offH     = 73662464;                // 67108864
    const size_t needed   = 140771328;
    if (ws_size < needed) return;

    char* w = (char*)d_ws;
    __hip_bfloat16* Wx0p  = (__hip_bfloat16*)(w + offWx0p);
    __hip_bfloat16* Wh0p  = (__hip_bfloat16*)(w + offWh0p);
    __hip_bfloat16* Wx1hp = (__hip_bfloat16*)(w + offWx1hp);
    __hip_bfloat16* Wh1p  = (__hip_bfloat16*)(w + offWh1p);
    float* cws = (float*)(w + offC);
    float* hws = (float*)(w + offH);

    dim3 blk(256);
    wprep_kernel<<<(2048 * 64 + 255) / 256, blk, 0, stream>>>(Wx0, Wx0p, 1, 0);
    wprep_kernel<<<(2048 * 512 + 255) / 256, blk, 0, stream>>>(Wh0, Wh0p, 4, 0);
    wprep_kernel<<<(2048 * 512 + 255) / 256, blk, 0, stream>>>(Wx1, Wx1hp, 4, 1);  // skip flag row
    wprep_kernel<<<(2048 * 512 + 255) / 256, blk, 0, stream>>>(Wh1, Wh1p, 4, 0);

    lstm_main<<<256, 1024, 0, stream>>>(x, b0, Wx1, b1, Wlin, blin,
                                        Wx0p, Wh0p, Wx1hp, Wh1p, cws, hws, (float*)d_out);
}

// Round 10
// 4980.404 us; speedup vs baseline: 2.1320x; 2.1320x over previous
//
#include <hip/hip_runtime.h>
#include <hip/hip_bf16.h>

// SSNet: 2-layer flag-gated LSTM, persistent-tile MFMA implementation.
// B=16384, T=32, IN=64, H=512, OUT=19.
// R10: 512-thread WG (8 waves). Discovery: hipcc budgets VGPR =
// 65536/block_threads regardless of LDS-capped occupancy (1024thr -> 64
// regs, unfixable via attributes; 512thr -> 128). New wave tile:
// 64 rows (4 rt) x 16 h-cols x 4 gates, 4 sb iters -> acc 64 + depth-2
// B pipeline fits 128 regs AND halves B traffic (4x row reuse, zero
// duplication: 6.4 MB/CU/step minimum). sb loop rolled (I-cache); h_new
// round-trips via hws (normal stores, L2-hot readback refills LDS after
// sync); c streams nt (HBM).

#define T_STEPS 32
#define IN_F    64
#define HID     512
#define OUT_F   19
#define BW      64   // batch rows per WG

typedef short bf16x8 __attribute__((ext_vector_type(8)));   // 8 bf16 = 4 VGPRs
typedef float f32x4  __attribute__((ext_vector_type(4)));

__device__ __forceinline__ float fast_sig(float x) {
    return __builtin_amdgcn_rcpf(1.0f + __expf(-x));
}
__device__ __forceinline__ float fast_tanh(float x) {
    return 1.0f - 2.0f * __builtin_amdgcn_rcpf(1.0f + __expf(2.0f * x));
}

// Light barrier: LDS hazards only (don't drain vmcnt).
#define LBAR() do { \
    asm volatile("s_waitcnt lgkmcnt(0)" ::: "memory"); \
    __builtin_amdgcn_sched_barrier(0); \
    __builtin_amdgcn_s_barrier(); \
    __builtin_amdgcn_sched_barrier(0); \
} while (0)

// 4 row-tiles x 4 gates
#define MFMA16(A0, A1, A2, A3, Q0, Q1, Q2, Q3) do { \
    acc[0][0] = __builtin_amdgcn_mfma_f32_16x16x32_bf16(A0, Q0, acc[0][0], 0, 0, 0); \
    acc[1][0] = __builtin_amdgcn_mfma_f32_16x16x32_bf16(A1, Q0, acc[1][0], 0, 0, 0); \
    acc[2][0] = __builtin_amdgcn_mfma_f32_16x16x32_bf16(A2, Q0, acc[2][0], 0, 0, 0); \
    acc[3][0] = __builtin_amdgcn_mfma_f32_16x16x32_bf16(A3, Q0, acc[3][0], 0, 0, 0); \
    acc[0][1] = __builtin_amdgcn_mfma_f32_16x16x32_bf16(A0, Q1, acc[0][1], 0, 0, 0); \
    acc[1][1] = __builtin_amdgcn_mfma_f32_16x16x32_bf16(A1, Q1, acc[1][1], 0, 0, 0); \
    acc[2][1] = __builtin_amdgcn_mfma_f32_16x16x32_bf16(A2, Q1, acc[2][1], 0, 0, 0); \
    acc[3][1] = __builtin_amdgcn_mfma_f32_16x16x32_bf16(A3, Q1, acc[3][1], 0, 0, 0); \
    acc[0][2] = __builtin_amdgcn_mfma_f32_16x16x32_bf16(A0, Q2, acc[0][2], 0, 0, 0); \
    acc[1][2] = __builtin_amdgcn_mfma_f32_16x16x32_bf16(A1, Q2, acc[1][2], 0, 0, 0); \
    acc[2][2] = __builtin_amdgcn_mfma_f32_16x16x32_bf16(A2, Q2, acc[2][2], 0, 0, 0); \
    acc[3][2] = __builtin_amdgcn_mfma_f32_16x16x32_bf16(A3, Q2, acc[3][2], 0, 0, 0); \
    acc[0][3] = __builtin_amdgcn_mfma_f32_16x16x32_bf16(A0, Q3, acc[0][3], 0, 0, 0); \
    acc[1][3] = __builtin_amdgcn_mfma_f32_16x16x32_bf16(A1, Q3, acc[1][3], 0, 0, 0); \
    acc[2][3] = __builtin_amdgcn_mfma_f32_16x16x32_bf16(A2, Q3, acc[2][3], 0, 0, 0); \
    acc[3][3] = __builtin_amdgcn_mfma_f32_16x16x32_bf16(A3, Q3, acc[3][3], 0, 0, 0); \
} while (0)

// Packed B layout, per 16-col block cb of the 2048 gate-cols:
//   dst[cb*(K*16) + kc*512 + l15*32 + lq*8 + e] = W[kc*32+lq*8+e + rowOff][cb*16+l15]
__global__ void wprep_kernel(const float* __restrict__ src,
                             __hip_bfloat16* __restrict__ dst,
                             int kcBits, int rowOff) {
    int idx = blockIdx.x * 256 + threadIdx.x;
    int total = 2048 << (kcBits + 5);
    if (idx >= total) return;
    int e   = idx & 7;
    int lq  = (idx >> 3) & 3;
    int l15 = (idx >> 5) & 15;
    int kc  = (idx >> 9) & ((1 << kcBits) - 1);
    int cb  = idx >> (9 + kcBits);
    int k   = kc * 32 + lq * 8 + e + rowOff;
    int col = cb * 16 + l15;
    dst[idx] = __float2bfloat16(src[(size_t)k * 2048 + col]);
}

// KC chunks, depth-2 rotated B pipeline, 4 row-tiles (stride RTS bytes).
template<int KC, int RTS>
__device__ __forceinline__ void gemm_sec4(const char* aE, const char* aO,
                                          const __hip_bfloat16* b0p,
                                          const __hip_bfloat16* b1p,
                                          const __hip_bfloat16* b2p,
                                          const __hip_bfloat16* b3p,
                                          f32x4 acc[4][4]) {
    bf16x8 pa0, pa1, pa2, pa3, pb0, pb1, pb2, pb3, a0, a1, a2, a3;
    pa0 = *(const bf16x8*)(b0p);
    pa1 = *(const bf16x8*)(b1p);
    pa2 = *(const bf16x8*)(b2p);
    pa3 = *(const bf16x8*)(b3p);
    #pragma unroll 1
    for (int m = 0; m < KC - 2; m += 2) {
        const int ao = (m >> 1) * 128;
        pb0 = *(const bf16x8*)(b0p + (m + 1) * 512);
        pb1 = *(const bf16x8*)(b1p + (m + 1) * 512);
        pb2 = *(const bf16x8*)(b2p + (m + 1) * 512);
        pb3 = *(const bf16x8*)(b3p + (m + 1) * 512);
        a0 = *(const bf16x8*)(aE + ao);
        a1 = *(const bf16x8*)(aE + RTS + ao);
        a2 = *(const bf16x8*)(aE + 2 * RTS + ao);
        a3 = *(const bf16x8*)(aE + 3 * RTS + ao);
        MFMA16(a0, a1, a2, a3, pa0, pa1, pa2, pa3);
        pa0 = *(const bf16x8*)(b0p + (m + 2) * 512);
        pa1 = *(const bf16x8*)(b1p + (m + 2) * 512);
        pa2 = *(const bf16x8*)(b2p + (m + 2) * 512);
        pa3 = *(const bf16x8*)(b3p + (m + 2) * 512);
        a0 = *(const bf16x8*)(aO + ao);
        a1 = *(const bf16x8*)(aO + RTS + ao);
        a2 = *(const bf16x8*)(aO + 2 * RTS + ao);
        a3 = *(const bf16x8*)(aO + 3 * RTS + ao);
        MFMA16(a0, a1, a2, a3, pb0, pb1, pb2, pb3);
    }
    {   // tail: chunks KC-2 (in pa) and KC-1
        const int ao = ((KC - 2) >> 1) * 128;
        pb0 = *(const bf16x8*)(b0p + (KC - 1) * 512);
        pb1 = *(const bf16x8*)(b1p + (KC - 1) * 512);
        pb2 = *(const bf16x8*)(b2p + (KC - 1) * 512);
        pb3 = *(const bf16x8*)(b3p + (KC - 1) * 512);
        a0 = *(const bf16x8*)(aE + ao);
        a1 = *(const bf16x8*)(aE + RTS + ao);
        a2 = *(const bf16x8*)(aE + 2 * RTS + ao);
        a3 = *(const bf16x8*)(aE + 3 * RTS + ao);
        MFMA16(a0, a1, a2, a3, pa0, pa1, pa2, pa3);
        a0 = *(const bf16x8*)(aO + ao);
        a1 = *(const bf16x8*)(aO + RTS + ao);
        a2 = *(const bf16x8*)(aO + 2 * RTS + ao);
        a3 = *(const bf16x8*)(aO + 3 * RTS + ao);
        MFMA16(a0, a1, a2, a3, pb0, pb1, pb2, pb3);
    }
}

__global__ __launch_bounds__(512, 2)
void lstm_main(const float* __restrict__ x,
               const float* __restrict__ b0v,
               const float* __restrict__ Wx1,     // row 0 = flag weights (f32)
               const float* __restrict__ b1v,
               const float* __restrict__ Wlin,
               const float* __restrict__ blin,
               const __hip_bfloat16* __restrict__ Wx0p,
               const __hip_bfloat16* __restrict__ Wh0p,
               const __hip_bfloat16* __restrict__ Wx1hp,
               const __hip_bfloat16* __restrict__ Wh1p,
               float* __restrict__ cws,
               float* __restrict__ hws,
               float* __restrict__ out)
{
    // LDS h tiles: row-major bf16, row stride 1024B, XOR-swizzle (row&7)<<4
    __shared__ __align__(16) __hip_bfloat16 h0s[BW * HID];   // 64 KB
    __shared__ __align__(16) __hip_bfloat16 h1s[BW * HID];   // 64 KB
    __shared__ __align__(16) __hip_bfloat16 xs[BW * IN_F];   // 8 KB, row stride 128B
    __shared__ float flags[BW];

    const int tid  = threadIdx.x;
    const int lane = tid & 63;
    const int wid  = tid >> 6;      // 0..7
    const int l15  = lane & 15;
    const int lq   = lane >> 4;
    const int lq16 = lq * 16;
    const int laneoff = l15 * 32 + lq * 8;   // elems within packed 512-elem chunk
    const int asw  = (l15 & 7) << 4;
    const int wg   = blockIdx.x;
    const size_t bbase = (size_t)wg * BW;
    const char* xsC = (const char*)xs;
    const char* h0C = (const char*)h0s;

    // pre-swizzled A bases for row-tile 0 (rt offset = rt*16*rowstride)
    const int swE = lq16 ^ asw;
    const int swO = (64 + lq16) ^ asw;
    const char* ahE = h0C + l15 * 1024 + swE;
    const char* ahO = h0C + l15 * 1024 + swO;
    const int h1d = (int)((const char*)h1s - (const char*)h0s);
    const char* axE = xsC + l15 * 128 + swE;
    const char* axO = xsC + l15 * 128 + swO;

    // zero h LDS
    {
        int4 z; z.x = z.y = z.z = z.w = 0;
        int4* p0 = (int4*)h0s; int4* p1 = (int4*)h1s;
        for (int i = tid; i < BW * HID * 2 / 16; i += 512) { p0[i] = z; p1[i] = z; }
    }
    // stage x(0) + flags
    for (int i = tid; i < BW * IN_F; i += 512) {
        int row = i >> 6, k = i & 63;
        float v = __builtin_nontemporal_load(&x[(bbase + row) * (T_STEPS * IN_F) + k]);
        int byte = row * 128 + ((2 * k) ^ ((row & 7) << 4));
        *(__hip_bfloat16*)((char*)xs + byte) = __float2bfloat16(v);
    }
    if (tid < BW) flags[tid] = x[(bbase + tid) * (T_STEPS * IN_F)];
    LBAR();

    const size_t wsWG0 = (size_t)(0 * 256 + wg) * 32768;   // floats
    const size_t wsWG1 = (size_t)(1 * 256 + wg) * 32768;

    #pragma unroll 1
    for (int t = 0; t < T_STEPS; ++t) {
        // ================= Layer 0: g0 = x@Wx0 + h0@Wh0 + b0 =================
        #pragma unroll 1
        for (int sb = 0; sb < 4; ++sb) {
            const int b2 = sb * 8 + wid;     // h-col block 0..31 (wave-uniform)
            f32x4 acc[4][4];
            { f32x4 zz = {0.f, 0.f, 0.f, 0.f};
              #pragma unroll
              for (int rt = 0; rt < 4; ++rt)
                  #pragma unroll
                  for (int g = 0; g < 4; ++g) acc[rt][g] = zz; }

            // x part: 2 chunks straight-line
            {
                const __hip_bfloat16* bx0 = Wx0p + (size_t)(0 * 32 + b2) * 1024 + laneoff;
                const __hip_bfloat16* bx1 = Wx0p + (size_t)(1 * 32 + b2) * 1024 + laneoff;
                const __hip_bfloat16* bx2 = Wx0p + (size_t)(2 * 32 + b2) * 1024 + laneoff;
                const __hip_bfloat16* bx3 = Wx0p + (size_t)(3 * 32 + b2) * 1024 + laneoff;
                bf16x8 pa0 = *(const bf16x8*)(bx0);
                bf16x8 pa1 = *(const bf16x8*)(bx1);
                bf16x8 pa2 = *(const bf16x8*)(bx2);
                bf16x8 pa3 = *(const bf16x8*)(bx3);
                bf16x8 pb0 = *(const bf16x8*)(bx0 + 512);
                bf16x8 pb1 = *(const bf16x8*)(bx1 + 512);
                bf16x8 pb2 = *(const bf16x8*)(bx2 + 512);
                bf16x8 pb3 = *(const bf16x8*)(bx3 + 512);
                bf16x8 a0 = *(const bf16x8*)(axE);
                bf16x8 a1 = *(const bf16x8*)(axE + 2048);
                bf16x8 a2 = *(const bf16x8*)(axE + 4096);
                bf16x8 a3 = *(const bf16x8*)(axE + 6144);
                MFMA16(a0, a1, a2, a3, pa0, pa1, pa2, pa3);
                a0 = *(const bf16x8*)(axO);
                a1 = *(const bf16x8*)(axO + 2048);
                a2 = *(const bf16x8*)(axO + 4096);
                a3 = *(const bf16x8*)(axO + 6144);
                MFMA16(a0, a1, a2, a3, pb0, pb1, pb2, pb3);
            }
            gemm_sec4<16, 16384>(ahE, ahO,
                Wh0p + (size_t)(0 * 32 + b2) * 8192 + laneoff,
                Wh0p + (size_t)(1 * 32 + b2) * 8192 + laneoff,
                Wh0p + (size_t)(2 * 32 + b2) * 8192 + laneoff,
                Wh0p + (size_t)(3 * 32 + b2) * 8192 + laneoff, acc);

            // epilogue
            const size_t sbase = wsWG0 + (size_t)b2 * 1024 + lane * 4;
            const int jcol = b2 * 16 + l15;
            float bia[4];
            #pragma unroll
            for (int g = 0; g < 4; ++g) bia[g] = b0v[g * 512 + jcol];
            #pragma unroll
            for (int rt = 0; rt < 4; ++rt) {
                f32x4 cold, hold;
                if (t > 0) {
                    cold = __builtin_nontemporal_load((const f32x4*)(cws + sbase + rt * 256));
                    hold = *(const f32x4*)(hws + sbase + rt * 256);
                } else {
                    f32x4 zz = {0.f, 0.f, 0.f, 0.f}; cold = zz; hold = zz;
                }
                f32x4 cnew, hnew;
                #pragma unroll
                for (int r = 0; r < 4; ++r) {
                    const float f = flags[rt * 16 + lq * 4 + r];
                    float gi = acc[rt][0][r] + bia[0];
                    float gf = acc[rt][1][r] + bia[1];
                    float gg = acc[rt][2][r] + bia[2];
                    float go = acc[rt][3][r] + bia[3];
                    float cn = fast_sig(gf) * cold[r] + fast_sig(gi) * fast_tanh(gg);
                    float hn = fast_sig(go) * fast_tanh(cn);
                    cnew[r] = f * cn + (1.f - f) * cold[r];
                    hnew[r] = f * hn + (1.f - f) * hold[r];
                }
                __builtin_nontemporal_store(cnew, (f32x4*)(cws + sbase + rt * 256));
                *(f32x4*)(hws + sbase + rt * 256) = hnew;
            }
        }
        __syncthreads();   // hws complete; everyone done reading h0s/xs

        // refill h0s (bf16, swizzled) from hws
        for (int i4 = tid; i4 < BW * HID / 4; i4 += 512) {
            f32x4 v = *(const f32x4*)(hws + wsWG0 + (size_t)i4 * 4);
            int lane2 = i4 & 63, rt2 = (i4 >> 6) & 3, b2r = i4 >> 8;
            int col2 = 2 * (b2r * 16 + (lane2 & 15));
            int rowb = rt2 * 16 + (lane2 >> 4) * 4;
            #pragma unroll
            for (int r = 0; r < 4; ++r) {
                int row = rowb + r;
                int byte = row * 1024 + (col2 ^ ((row & 7) << 4));
                *(__hip_bfloat16*)((char*)h0s + byte) = __float2bfloat16(v[r]);
            }
        }
        LBAR();   // new h0s visible

        // ===== Layer 1: g1 = flag*Wx1[0] + h0_new@Wx1[1:] + h1@Wh1 + b1 =====
        #pragma unroll 1
        for (int sb = 0; sb < 4; ++sb) {
            const int b2 = sb * 8 + wid;
            f32x4 acc[4][4];
            { f32x4 zz = {0.f, 0.f, 0.f, 0.f};
              #pragma unroll
              for (int rt = 0; rt < 4; ++rt)
                  #pragma unroll
                  for (int g = 0; g < 4; ++g) acc[rt][g] = zz; }

            gemm_sec4<16, 16384>(ahE, ahO,
                Wx1hp + (size_t)(0 * 32 + b2) * 8192 + laneoff,
                Wx1hp + (size_t)(1 * 32 + b2) * 8192 + laneoff,
                Wx1hp + (size_t)(2 * 32 + b2) * 8192 + laneoff,
                Wx1hp + (size_t)(3 * 32 + b2) * 8192 + laneoff, acc);
            gemm_sec4<16, 16384>(ahE + h1d, ahO + h1d,
                Wh1p + (size_t)(0 * 32 + b2) * 8192 + laneoff,
                Wh1p + (size_t)(1 * 32 + b2) * 8192 + laneoff,
                Wh1p + (size_t)(2 * 32 + b2) * 8192 + laneoff,
                Wh1p + (size_t)(3 * 32 + b2) * 8192 + laneoff, acc);

            const size_t sbase = wsWG1 + (size_t)b2 * 1024 + lane * 4;
            const int jcol = b2 * 16 + l15;
            float bia[4], w10[4];
            #pragma unroll
            for (int g = 0; g < 4; ++g) {
                bia[g] = b1v[g * 512 + jcol];
                w10[g] = Wx1[g * 512 + jcol];
            }
            #pragma unroll
            for (int rt = 0; rt < 4; ++rt) {
                f32x4 cold, hold;
                if (t > 0) {
                    cold = __builtin_nontemporal_load((const f32x4*)(cws + sbase + rt * 256));
                    hold = *(const f32x4*)(hws + sbase + rt * 256);
                } else {
                    f32x4 zz = {0.f, 0.f, 0.f, 0.f}; cold = zz; hold = zz;
                }
                f32x4 cnew, hnew;
                #pragma unroll
                for (int r = 0; r < 4; ++r) {
                    const float f = flags[rt * 16 + lq * 4 + r];
                    float gi = acc[rt][0][r] + bia[0] + f * w10[0];
                    float gf = acc[rt][1][r] + bia[1] + f * w10[1];
                    float gg = acc[rt][2][r] + bia[2] + f * w10[2];
                    float go = acc[rt][3][r] + bia[3] + f * w10[3];
                    float cn = fast_sig(gf) * cold[r] + fast_sig(gi) * fast_tanh(gg);
                    float hn = fast_sig(go) * fast_tanh(cn);
                    cnew[r] = f * cn + (1.f - f) * cold[r];
                    hnew[r] = f * hn + (1.f - f) * hold[r];
                }
                __builtin_nontemporal_store(cnew, (f32x4*)(cws + sbase + rt * 256));
                *(f32x4*)(hws + sbase + rt * 256) = hnew;
            }
        }
        __syncthreads();   // hws(L1) complete; done reading h0s/h1s

        // refill h1s from hws; stage x(t+1) + flags
        for (int i4 = tid; i4 < BW * HID / 4; i4 += 512) {
            f32x4 v = *(const f32x4*)(hws + wsWG1 + (size_t)i4 * 4);
            int lane2 = i4 & 63, rt2 = (i4 >> 6) & 3, b2r = i4 >> 8;
            int col2 = 2 * (b2r * 16 + (lane2 & 15));
            int rowb = rt2 * 16 + (lane2 >> 4) * 4;
            #pragma unroll
            for (int r = 0; r < 4; ++r) {
                int row = rowb + r;
                int byte = row * 1024 + (col2 ^ ((row & 7) << 4));
                *(__hip_bfloat16*)((char*)h1s + byte) = __float2bfloat16(v[r]);
            }
        }
        if (t + 1 < T_STEPS) {
            for (int i = tid; i < BW * IN_F; i += 512) {
                int row = i >> 6, k = i & 63;
                float v = __builtin_nontemporal_load(&x[(bbase + row) * (T_STEPS * IN_F) + (t + 1) * IN_F + k]);
                int byte = row * 128 + ((2 * k) ^ ((row & 7) << 4));
                *(__hip_bfloat16*)((char*)xs + byte) = __float2bfloat16(v);
            }
            if (tid < BW) flags[tid] = x[(bbase + tid) * (T_STEPS * IN_F) + (t + 1) * IN_F];
        }
        LBAR();   // h1s/xs/flags ready for next step
    }

    // ---- final linear: out = h1 @ Wlin + blin  (64x512 @ 512x19) ----
    for (int task = tid; task < BW * OUT_F; task += 512) {
        int o   = task >> 6;     // wave-uniform
        int row = task & 63;
        float s = blin[o];
        const float* wl = Wlin + o;
        for (int k = 0; k < HID; ++k) {
            int byte = row * 1024 + ((2 * k) ^ ((row & 7) << 4));
            float hv = __bfloat162float(*(const __hip_bfloat16*)((const char*)h1s + byte));
            s += hv * wl[k * OUT_F];
        }
        out[(bbase + row) * OUT_F + o] = s;
    }
}

extern "C" void kernel_launch(void* const* d_in, const int* in_sizes, int n_in,
                              void* d_out, int out_size, void* d_ws, size_t ws_size,
                              hipStream_t stream) {
    const float* x    = (const float*)d_in[0];
    const float* Wx0  = (const float*)d_in[1];
    const float* Wh0  = (const float*)d_in[2];
    const float* b0   = (const float*)d_in[3];
    const float* Wx1  = (const float*)d_in[4];
    const float* Wh1  = (const float*)d_in[5];
    const float* b1   = (const float*)d_in[6];
    const float* Wlin = (const float*)d_in[7];
    const float* blin = (const float*)d_in[8];

    // workspace carve (bytes)
    const size_t offWx0p  = 0;                       // 2048*64*2   = 262144
    const size_t offWh0p  = 262144;                  // 2048*512*2  = 2097152
    const size_t offWx1hp = 2359296;
    const size_t offWh1p  = 4456448;
    const size_t offC     = 6553600;                 // 2*256*32768*4 = 67108864
    const size_t offH     = 73662464;                // 67108864
    const size_t needed   = 140771328;
    if (ws_size < needed) return;

    char* w = (char*)d_ws;
    __hip_bfloat16* Wx0p  = (__hip_bfloat16*)(w + offWx0p);
    __hip_bfloat16* Wh0p  = (__hip_bfloat16*)(w + offWh0p);
    __hip_bfloat16* Wx1hp = (__hip_bfloat16*)(w + offWx1hp);
    __hip_bfloat16* Wh1p  = (__hip_bfloat16*)(w + offWh1p);
    float* cws = (float*)(w + offC);
    float* hws = (float*)(w + offH);

    dim3 blk(256);
    wprep_kernel<<<(2048 * 64 + 255) / 256, blk, 0, stream>>>(Wx0, Wx0p, 1, 0);
    wprep_kernel<<<(2048 * 512 + 255) / 256, blk, 0, stream>>>(Wh0, Wh0p, 4, 0);
    wprep_kernel<<<(2048 * 512 + 255) / 256, blk, 0, stream>>>(Wx1, Wx1hp, 4, 1);  // skip flag row
    wprep_kernel<<<(2048 * 512 + 255) / 256, blk, 0, stream>>>(Wh1, Wh1p, 4, 0);

    lstm_main<<<256, 512, 0, stream>>>(x, b0, Wx1, b1, Wlin, blin,
                                       Wx0p, Wh0p, Wx1hp, Wh1p, cws, hws, (float*)d_out);
}